// Round 11
// baseline (18.777 us; speedup 1.0000x reference)
//
#include <hip/hip_runtime.h>
#include <math.h>

#define ALPHA 0.5

typedef float v2f __attribute__((ext_vector_type(2)));

constexpr int BLK = 256;      // threads per block
constexpr int IBLK = 4;       // i-values per thread (register tile)
constexpr int JCHUNK = 64;    // j-elements staged in LDS per block

// Pairwise hinge partials (+ MSE folded into blockIdx.y==0 blocks).
// Grid: (n/(BLK*IBLK)) x (n/JCHUNK) = 8 x 128 = 1024 blocks (4/CU).
// Count via ballot+popcount (SALU pipe, R10: -1.3us). This round: j-values
// processed as float2 with ext-vector arithmetic so the backend can form
// v_pk_add_f32 (CDNA4 64-bit VALU lanes: 2 f32 adds per issue slot) for the
// hinge-argument add and the accumulate -> 5 -> 4 VALU slots per pair.
__global__ __launch_bounds__(BLK, 4) void pair_partial_kernel(
    const float* __restrict__ logits,
    const float* __restrict__ labels,
    double* __restrict__ partial,   // [nblocks][4] = {hinge, count, mse, pad}
    int n)
{
    __shared__ float s_lab[JCHUNK];
    __shared__ float s_log[JCHUNK];
    __shared__ double s_red[BLK / 64][3];

    const int tid = threadIdx.x;
    const int ib = (blockIdx.x * BLK + tid) * IBLK;
    const int j0 = blockIdx.y * JCHUNK;
    const int jlen = min(JCHUNK, n - j0);

    if (tid < jlen) {
        s_lab[tid] = labels[j0 + tid];
        s_log[tid] = logits[j0 + tid];
    }
    __syncthreads();

    float yi[IBLK];
    v2f ai2[IBLK];                  // (1 - logit_i) replicated in both halves
    v2f hsum2[IBLK];                // packed accumulators
    float msum = 0.0f;
    unsigned int cntw = 0;          // wave-uniform (ballot popcount) -> SGPR
    const bool doMse = (blockIdx.y == 0);

#pragma unroll
    for (int u = 0; u < IBLK; ++u) hsum2[u] = (v2f)(0.0f);

    if (ib + IBLK <= n) {
        const float4 yv = *reinterpret_cast<const float4*>(labels + ib);
        const float4 lv = *reinterpret_cast<const float4*>(logits + ib);
#pragma unroll
        for (int u = 0; u < IBLK; ++u) {
            const float y = (&yv.x)[u], l = (&lv.x)[u];
            yi[u] = y;
            const float a = 1.0f - l;
            ai2[u] = (v2f){a, a};
            if (doMse) { const float d = l - y; msum += d * d; }
        }
    } else {
#pragma unroll
        for (int u = 0; u < IBLK; ++u) {
            const int i = ib + u;
            const bool v = i < n;
            const float y = v ? labels[i] : 0.0f;
            const float l = v ? logits[i] : 0.0f;
            yi[u] = v ? y : -INFINITY;   // mask never true for inactive lanes
            const float a = 1.0f - l;
            ai2[u] = (v2f){a, a};
            if (doMse && v) { const float d = l - y; msum += d * d; }
        }
    }

    const v2f zero2 = (v2f)(0.0f);
    const int jlen4 = jlen >> 2;
    const float4* lab4 = reinterpret_cast<const float4*>(s_lab);
    const float4* log4 = reinterpret_cast<const float4*>(s_log);
#pragma unroll 2
    for (int jj = 0; jj < jlen4; ++jj) {
        const float4 yb = lab4[jj];
        const float4 lb = log4[jj];
        const v2f yjp[2] = {{yb.x, yb.y}, {yb.z, yb.w}};
        const v2f ljp[2] = {{lb.x, lb.y}, {lb.z, lb.w}};
#pragma unroll
        for (int p = 0; p < 2; ++p) {
#pragma unroll
            for (int u = 0; u < IBLK; ++u) {
                const v2f t = ai2[u] + ljp[p];                    // v_pk_add_f32
                const v2f h = __builtin_elementwise_max(t, zero2); // 2x v_max
                const bool m0 = yi[u] > yjp[p].x;                 // v_cmp
                const bool m1 = yi[u] > yjp[p].y;                 // v_cmp
                v2f ctr;
                ctr.x = m0 ? h.x : 0.0f;                          // cndmask
                ctr.y = m1 ? h.y : 0.0f;                          // cndmask
                hsum2[u] += ctr;                                  // v_pk_add_f32
                cntw += (unsigned)__popcll(__ballot(m0));         // SALU
                cntw += (unsigned)__popcll(__ballot(m1));         // SALU
            }
        }
    }
    for (int j = jlen4 << 2; j < jlen; ++j) {   // tail (unused for n%64==0)
        const float yj = s_lab[j], lj = s_log[j];
#pragma unroll
        for (int u = 0; u < IBLK; ++u) {
            const float h = fmaxf(ai2[u].x + lj, 0.0f);
            const bool m = yi[u] > yj;
            hsum2[u].x += m ? h : 0.0f;
            cntw += (unsigned)__popcll(__ballot(m));
        }
    }

    float hs = 0.0f;
#pragma unroll
    for (int u = 0; u < IBLK; ++u) hs += hsum2[u].x + hsum2[u].y;
    for (int off = 32; off > 0; off >>= 1)
        hs += __shfl_down(hs, off, 64);
    if (doMse) {
        for (int off = 32; off > 0; off >>= 1)
            msum += __shfl_down(msum, off, 64);
    }
    const int wave = tid >> 6;
    if ((tid & 63) == 0) {
        s_red[wave][0] = (double)hs;
        s_red[wave][1] = (double)cntw;   // uniform across the wave
        s_red[wave][2] = (double)msum;
    }
    __syncthreads();
    if (tid == 0) {
        double s = 0.0, c = 0.0, m2 = 0.0;
        for (int w = 0; w < BLK / 64; ++w) {
            s += s_red[w][0]; c += s_red[w][1]; m2 += s_red[w][2];
        }
        const int b = blockIdx.y * gridDim.x + blockIdx.x;
        partial[4 * b + 0] = s;
        partial[4 * b + 1] = c;
        partial[4 * b + 2] = m2;
    }
}

// One block: reduce 1024 partial triples (L2-resident, ~24 KB), write scalar.
__global__ __launch_bounds__(BLK) void finalize_kernel(
    const double* __restrict__ partial,
    int nPartial, int n,
    float* __restrict__ out)
{
    __shared__ double s_red[BLK / 64][3];
    const int tid = threadIdx.x;

    double s = 0.0, c = 0.0, m2 = 0.0;
    for (int b = tid; b < nPartial; b += BLK) {
        s  += partial[4 * b + 0];
        c  += partial[4 * b + 1];
        m2 += partial[4 * b + 2];
    }
    for (int off = 32; off > 0; off >>= 1) {
        s  += __shfl_down(s, off, 64);
        c  += __shfl_down(c, off, 64);
        m2 += __shfl_down(m2, off, 64);
    }
    const int wave = tid >> 6;
    if ((tid & 63) == 0) {
        s_red[wave][0] = s; s_red[wave][1] = c; s_red[wave][2] = m2;
    }
    __syncthreads();
    if (tid == 0) {
        double S = 0.0, C = 0.0, M = 0.0;
        for (int w = 0; w < BLK / 64; ++w) {
            S += s_red[w][0]; C += s_red[w][1]; M += s_red[w][2];
        }
        const double mse = M / (double)n;
        const double ranking = (C > 0.0) ? (S / C) : 0.0;
        out[0] = (float)(ALPHA * mse + (1.0 - ALPHA) * ranking);
    }
}

extern "C" void kernel_launch(void* const* d_in, const int* in_sizes, int n_in,
                              void* d_out, int out_size, void* d_ws, size_t ws_size,
                              hipStream_t stream) {
    const float* logits = (const float*)d_in[0];
    const float* labels = (const float*)d_in[1];
    const int n = in_sizes[0];

    const int gx = (n + BLK * IBLK - 1) / (BLK * IBLK);  // 8 for n=8192
    const int gy = (n + JCHUNK - 1) / JCHUNK;            // 128 for n=8192
    const int nblocks = gx * gy;                         // 1024

    double* partial = (double*)d_ws;                     // 32 KB

    pair_partial_kernel<<<dim3(gx, gy), BLK, 0, stream>>>(logits, labels, partial, n);
    finalize_kernel<<<1, BLK, 0, stream>>>(partial, nblocks, n, (float*)d_out);
}

// Round 12
// 17.398 us; speedup vs baseline: 1.0792x; 1.0792x over previous
//
#include <hip/hip_runtime.h>
#include <math.h>

#define ALPHA 0.5

constexpr int BLK = 256;      // threads per block
constexpr int IBLK = 4;       // i-values per thread (register tile)
constexpr int JCHUNK = 64;    // j-elements staged in LDS per block

// Pairwise hinge partials (+ MSE folded into blockIdx.y==0 blocks).
// Grid: (n/(BLK*IBLK)) x (n/JCHUNK) = 8 x 128 = 1024 blocks (4/CU).
// Count accumulation via ballot+popcount: the v_cmp already feeds the
// cndmask; popcount of the (wave-uniform) ballot accumulates on the SALU
// pipe, cutting the per-pair VALU count from 6 to 5 and removing count
// from the shuffle reduce entirely. (R11's packed-v2f variant regressed:
// insert/extract traffic around the per-half cmps outweighed pk_add wins.)
__global__ __launch_bounds__(BLK, 4) void pair_partial_kernel(
    const float* __restrict__ logits,
    const float* __restrict__ labels,
    double* __restrict__ partial,   // [nblocks][4] = {hinge, count, mse, pad}
    int n)
{
    __shared__ float s_lab[JCHUNK];
    __shared__ float s_log[JCHUNK];
    __shared__ double s_red[BLK / 64][3];

    const int tid = threadIdx.x;
    const int ib = (blockIdx.x * BLK + tid) * IBLK;
    const int j0 = blockIdx.y * JCHUNK;
    const int jlen = min(JCHUNK, n - j0);

    if (tid < jlen) {
        s_lab[tid] = labels[j0 + tid];
        s_log[tid] = logits[j0 + tid];
    }
    __syncthreads();

    float yi[IBLK], ai[IBLK], hsum[IBLK];
    float msum = 0.0f;
    unsigned int cntw = 0;          // wave-uniform (ballot popcount) -> SGPR
    const bool doMse = (blockIdx.y == 0);

#pragma unroll
    for (int u = 0; u < IBLK; ++u) hsum[u] = 0.0f;

    if (ib + IBLK <= n) {
        const float4 yv = *reinterpret_cast<const float4*>(labels + ib);
        const float4 lv = *reinterpret_cast<const float4*>(logits + ib);
#pragma unroll
        for (int u = 0; u < IBLK; ++u) {
            const float y = (&yv.x)[u], l = (&lv.x)[u];
            yi[u] = y;
            ai[u] = 1.0f - l;
            if (doMse) { const float d = l - y; msum += d * d; }
        }
    } else {
#pragma unroll
        for (int u = 0; u < IBLK; ++u) {
            const int i = ib + u;
            const bool v = i < n;
            const float y = v ? labels[i] : 0.0f;
            const float l = v ? logits[i] : 0.0f;
            yi[u] = v ? y : -INFINITY;   // mask never true for inactive lanes
            ai[u] = 1.0f - l;
            if (doMse && v) { const float d = l - y; msum += d * d; }
        }
    }

    const int jlen4 = jlen >> 2;
    const float4* lab4 = reinterpret_cast<const float4*>(s_lab);
    const float4* log4 = reinterpret_cast<const float4*>(s_log);
#pragma unroll 2
    for (int jj = 0; jj < jlen4; ++jj) {
        const float4 yb = lab4[jj];
        const float4 lb = log4[jj];
#pragma unroll
        for (int c = 0; c < 4; ++c) {
            const float yj = (&yb.x)[c];
            const float lj = (&lb.x)[c];
#pragma unroll
            for (int u = 0; u < IBLK; ++u) {
                const float h = fmaxf(ai[u] + lj, 0.0f);  // relu(1 - (li - lj))
                const bool m = yi[u] > yj;
                hsum[u] += m ? h : 0.0f;
                cntw += (unsigned)__popcll(__ballot(m));  // SALU accumulate
            }
        }
    }
    for (int j = jlen4 << 2; j < jlen; ++j) {   // tail (unused for n%64==0)
        const float yj = s_lab[j], lj = s_log[j];
#pragma unroll
        for (int u = 0; u < IBLK; ++u) {
            const float h = fmaxf(ai[u] + lj, 0.0f);
            const bool m = yi[u] > yj;
            hsum[u] += m ? h : 0.0f;
            cntw += (unsigned)__popcll(__ballot(m));
        }
    }

    float hs = (hsum[0] + hsum[1]) + (hsum[2] + hsum[3]);
    for (int off = 32; off > 0; off >>= 1)
        hs += __shfl_down(hs, off, 64);
    if (doMse) {
        for (int off = 32; off > 0; off >>= 1)
            msum += __shfl_down(msum, off, 64);
    }
    const int wave = tid >> 6;
    if ((tid & 63) == 0) {
        s_red[wave][0] = (double)hs;
        s_red[wave][1] = (double)cntw;   // uniform across the wave
        s_red[wave][2] = (double)msum;
    }
    __syncthreads();
    if (tid == 0) {
        double s = 0.0, c = 0.0, m2 = 0.0;
        for (int w = 0; w < BLK / 64; ++w) {
            s += s_red[w][0]; c += s_red[w][1]; m2 += s_red[w][2];
        }
        const int b = blockIdx.y * gridDim.x + blockIdx.x;
        partial[4 * b + 0] = s;
        partial[4 * b + 1] = c;
        partial[4 * b + 2] = m2;
    }
}

// One block: reduce 1024 partial triples (L2-resident, ~24 KB), write scalar.
__global__ __launch_bounds__(BLK) void finalize_kernel(
    const double* __restrict__ partial,
    int nPartial, int n,
    float* __restrict__ out)
{
    __shared__ double s_red[BLK / 64][3];
    const int tid = threadIdx.x;

    double s = 0.0, c = 0.0, m2 = 0.0;
    for (int b = tid; b < nPartial; b += BLK) {
        s  += partial[4 * b + 0];
        c  += partial[4 * b + 1];
        m2 += partial[4 * b + 2];
    }
    for (int off = 32; off > 0; off >>= 1) {
        s  += __shfl_down(s, off, 64);
        c  += __shfl_down(c, off, 64);
        m2 += __shfl_down(m2, off, 64);
    }
    const int wave = tid >> 6;
    if ((tid & 63) == 0) {
        s_red[wave][0] = s; s_red[wave][1] = c; s_red[wave][2] = m2;
    }
    __syncthreads();
    if (tid == 0) {
        double S = 0.0, C = 0.0, M = 0.0;
        for (int w = 0; w < BLK / 64; ++w) {
            S += s_red[w][0]; C += s_red[w][1]; M += s_red[w][2];
        }
        const double mse = M / (double)n;
        const double ranking = (C > 0.0) ? (S / C) : 0.0;
        out[0] = (float)(ALPHA * mse + (1.0 - ALPHA) * ranking);
    }
}

extern "C" void kernel_launch(void* const* d_in, const int* in_sizes, int n_in,
                              void* d_out, int out_size, void* d_ws, size_t ws_size,
                              hipStream_t stream) {
    const float* logits = (const float*)d_in[0];
    const float* labels = (const float*)d_in[1];
    const int n = in_sizes[0];

    const int gx = (n + BLK * IBLK - 1) / (BLK * IBLK);  // 8 for n=8192
    const int gy = (n + JCHUNK - 1) / JCHUNK;            // 128 for n=8192
    const int nblocks = gx * gy;                         // 1024

    double* partial = (double*)d_ws;                     // 32 KB

    pair_partial_kernel<<<dim3(gx, gy), BLK, 0, stream>>>(logits, labels, partial, n);
    finalize_kernel<<<1, BLK, 0, stream>>>(partial, nblocks, n, (float*)d_out);
}